// Round 4
// baseline (16544.118 us; speedup 1.0000x reference)
//
#include <hip/hip_runtime.h>
#include <cstdint>

typedef _Float16 half_t;
typedef __attribute__((ext_vector_type(2))) _Float16 half2_t;
typedef __attribute__((ext_vector_type(4))) _Float16 half4_t;
typedef __attribute__((ext_vector_type(8))) _Float16 half8_t;
typedef __attribute__((ext_vector_type(4))) float f32x4;

#define B_    32
#define DIN   128
#define LEN   2048
#define DS    512
#define NKT   16                            // K-tiles of 32 (16x16x32 MFMA)
#define NMEM  8                             // blocks (members) per group (N-split)
#define FLAGS_BYTES 4096

__device__ __forceinline__ float fast_tanh(float x) {
    float e = __expf(2.0f * x);        // large |x| saturates correctly via inf/0
    return 1.0f - 2.0f / (e + 1.0f);
}

__device__ __forceinline__ float fd2(uint32_t a, uint32_t b, float c) {
    return __builtin_amdgcn_fdot2(__builtin_bit_cast(half2_t, a),
                                  __builtin_bit_cast(half2_t, b), c, false);
}

// B-fragment for 16x16x32: lane(c=lane&15, q=lane>>4) holds B[k0+q*8+j][n0+c]
// = W[n0+c][k0+q*8+j], j=0..7 -> 8 consecutive f32 from W row n0+c.
__device__ __forceinline__ half8_t load_wfrag(const float* __restrict__ W,
                                              int n0, int c, int q, int kt) {
    const float* p = W + (size_t)(n0 + c) * DS + kt * 32 + q * 8;
    float4 f0 = *(const float4*)p;
    float4 f1 = *(const float4*)(p + 4);
    half8_t r = {(half_t)f0.x, (half_t)f0.y, (half_t)f0.z, (half_t)f0.w,
                 (half_t)f1.x, (half_t)f1.y, (half_t)f1.z, (half_t)f1.w};
    return r;
}

// ---------------------------------------------------------------- kernel A
// pre[b][l][h] = sum_d x[b][d][l]*W_ih[h][d] + b_ih[h] + b_hh[h]   (f16 out)
// Also zeroes the recur-kernel sync flags (block (0,0,0) only) -- runs
// before recur on the same stream every launch/replay.
__global__ __launch_bounds__(256) void rnn_pre_kernel(
    const float* __restrict__ x, const float* __restrict__ Wih,
    const float* __restrict__ bih, const float* __restrict__ bhh,
    half_t* __restrict__ pre, uint32_t* __restrict__ flags)
{
    __shared__ half_t Xs[64 * 136];    // [l][d], stride 136
    __shared__ half_t Ws[128 * 136];   // [h][d], stride 136
    const int t  = threadIdx.x;
    const int l0 = blockIdx.x * 64;
    const int b  = blockIdx.y;
    const int h0 = blockIdx.z * 128;

    if (blockIdx.x == 0 && blockIdx.y == 0 && blockIdx.z == 0)
        flags[t] = 0;                  // 256 u32 >= all flag slots

#pragma unroll
    for (int i = 0; i < 32; ++i) {
        int idx = i * 256 + t;
        int j = idx & 63, d = idx >> 6;
        Xs[j * 136 + d] = (half_t)x[(size_t)b * DIN * LEN + (size_t)d * LEN + l0 + j];
    }
#pragma unroll
    for (int i = 0; i < 16; ++i) {
        int f4 = i * 256 + t;
        int h = f4 >> 5, d4 = f4 & 31;
        float4 w = *(const float4*)&Wih[(size_t)(h0 + h) * DIN + d4 * 4];
        half4_t hw = {(half_t)w.x, (half_t)w.y, (half_t)w.z, (half_t)w.w};
        *(half4_t*)&Ws[h * 136 + d4 * 4] = hw;
    }
    __syncthreads();

    const int lb = (t >> 4) * 4;
    const int hb = (t & 15) * 8;
    float acc[4][8];
#pragma unroll
    for (int i = 0; i < 4; ++i)
#pragma unroll
        for (int j = 0; j < 8; ++j) acc[i][j] = 0.f;

    for (int kc = 0; kc < DIN; kc += 8) {
        uint4 xa[4], wb[8];
#pragma unroll
        for (int i = 0; i < 4; ++i) xa[i] = *(const uint4*)&Xs[(lb + i) * 136 + kc];
#pragma unroll
        for (int j = 0; j < 8; ++j) wb[j] = *(const uint4*)&Ws[(hb + j) * 136 + kc];
#pragma unroll
        for (int i = 0; i < 4; ++i)
#pragma unroll
            for (int j = 0; j < 8; ++j) {
                float a = acc[i][j];
                a = fd2(xa[i].x, wb[j].x, a);
                a = fd2(xa[i].y, wb[j].y, a);
                a = fd2(xa[i].z, wb[j].z, a);
                a = fd2(xa[i].w, wb[j].w, a);
                acc[i][j] = a;
            }
    }

    float bias[8];
#pragma unroll
    for (int j = 0; j < 8; ++j) bias[j] = bih[h0 + hb + j] + bhh[h0 + hb + j];
#pragma unroll
    for (int i = 0; i < 4; ++i) {
        half8_t s;
#pragma unroll
        for (int j = 0; j < 8; ++j) s[j] = (half_t)(acc[i][j] + bias[j]);
        *(half8_t*)&pre[((size_t)b * LEN + l0 + lb + i) * DS + h0 + hb] = s;
    }
}

// ---------------------------------------------------------------- kernel B
// Batch-packed cooperative MFMA scan.
//   2 groups x 16 batches (M dim = 16 REAL batches, no replication waste).
//   Per group, N=512 split across NMEM=8 blocks (slice 64); block = 4 waves,
//   wave w owns n-tile n0 = m*64 + w*16 (16 MFMAs/step, K=512 = 16 kt).
//   W_hh slice fully register-resident (16 frags = 64 VGPRs/wave). No LDS.
//   h exchange through hs[] itself (global, L2/IF):
//     producer: stores slice -> __syncthreads (vmcnt0 drain) -> t0 release-
//               stores flag=l+1 (agent scope => wbl2 to Infinity Cache).
//     consumer: relaxed agent spins on the 7 other flags >= l, then
//               __threadfence (acquire: inv) -> plain A-frag loads.
//   Own slice needs no flag wait (program order + drain + dirty-L2 hit).
//   Grid 64, XCD-optimistic mapping: g = bid&7 (active iff <2), m = bid>>3
//   -- if placement is round-robin each group is XCD-local (speed only;
//   correctness is agent-scope regardless). Spin guard prevents hangs.
__global__ __launch_bounds__(256) void rnn_recur_kernel(
    const float* __restrict__ Whh, const half_t* __restrict__ pre,
    half_t* __restrict__ hs, uint32_t* __restrict__ flags)
{
    const int bid = blockIdx.x;
    const int g   = bid & 7;           // group if < 2, else idle
    const int m   = bid >> 3;          // member 0..7
    if (g >= 2) return;

    const int t    = threadIdx.x;
    const int w    = t >> 6;
    const int lane = t & 63;
    const int c    = lane & 15;
    const int q    = lane >> 4;
    const int n0   = m * 64 + w * 16;

    // W_hh fragments for rows [n0, n0+16), all 16 k-tiles: 64 VGPRs
    half8_t wf[NKT];
#pragma unroll
    for (int kt = 0; kt < NKT; ++kt) wf[kt] = load_wfrag(Whh, n0, c, q, kt);

    // pre pointers: batch rows g*16+q*4+r, column n0+c  (pre[b][l][h])
    const half_t* pp[4];
#pragma unroll
    for (int r = 0; r < 4; ++r)
        pp[r] = pre + ((size_t)(g * 16 + q * 4 + r) * LEN) * DS + n0 + c;

    float pvc[4], pvn[4];
#pragma unroll
    for (int r = 0; r < 4; ++r) {
        pvc[r] = (float)pp[r][0];          // l = 0
        pvn[r] = (float)pp[r][DS];         // l = 1
        pp[r] += 2 * (size_t)DS;           // -> row 2 (iter l loads row l+1)
    }

    // hs store base: row (l*B + g*16 + q*4), col n0+c; r at +DS offsets
    half_t* hsp = hs + (size_t)(g * 16 + q * 4) * DS + n0 + c;
    // A-frag load base for step l: row ((l-1)*B + g*16 + c), k-offset q*8
    const half_t* ap = hs + (size_t)(g * 16 + c) * DS + q * 8;

    uint32_t* fl = flags + g * 8 * 16;     // flag slots: 64B apart
    const int myf = m * 16;

    // ---- step 0: h_{-1} = 0 -> h_0 = tanh(pre_0)
#pragma unroll
    for (int r = 0; r < 4; ++r)
        hsp[(size_t)r * DS] = (half_t)fast_tanh(pvc[r]);
    __syncthreads();                       // emits vmcnt(0) drain + barrier
    if (t == 0)
        __hip_atomic_store(&fl[myf], 1u, __ATOMIC_RELEASE, __HIP_MEMORY_SCOPE_AGENT);
    hsp += (size_t)B_ * DS;
#pragma unroll
    for (int r = 0; r < 4; ++r) pvc[r] = pvn[r];

    for (int l = 1; l < LEN; ++l) {
        // prefetch pre row l+1 (clamped at 2047) -- overlaps the spin
#pragma unroll
        for (int r = 0; r < 4; ++r) pvn[r] = (float)pp[r][0];
        if (l <= LEN - 3) {
#pragma unroll
            for (int r = 0; r < 4; ++r) pp[r] += DS;
        }

        // wait for the 7 remote producers of h_{l-1} (own slice needs none)
        for (int i = 1; i < NMEM; ++i) {
            const uint32_t* f = &fl[((m + i) & 7) * 16];
            int guard = 0;
            while (__hip_atomic_load(f, __ATOMIC_RELAXED,
                                     __HIP_MEMORY_SCOPE_AGENT) < (uint32_t)l) {
                if (++guard > (1 << 22)) break;   // failsafe: no infinite hang
            }
        }
        __threadfence();                   // acquire: invalidate stale lines

        // A fragments: lane(c,q) = h_{l-1}[batch g*16+c][kt*32 + q*8 ..+8]
        half8_t a[NKT];
#pragma unroll
        for (int kt = 0; kt < NKT; ++kt)
            a[kt] = *(const half8_t*)(ap + kt * 32);

        // 4 independent accumulation chains (hide MFMA latency @1 wave/SIMD)
        f32x4 ac0 = {0.f, 0.f, 0.f, 0.f};
        f32x4 ac1 = {0.f, 0.f, 0.f, 0.f};
        f32x4 ac2 = {0.f, 0.f, 0.f, 0.f};
        f32x4 ac3 = {0.f, 0.f, 0.f, 0.f};
#pragma unroll
        for (int kt = 0; kt < NKT; kt += 4) {
            ac0 = __builtin_amdgcn_mfma_f32_16x16x32_f16(a[kt + 0], wf[kt + 0], ac0, 0, 0, 0);
            ac1 = __builtin_amdgcn_mfma_f32_16x16x32_f16(a[kt + 1], wf[kt + 1], ac1, 0, 0, 0);
            ac2 = __builtin_amdgcn_mfma_f32_16x16x32_f16(a[kt + 2], wf[kt + 2], ac2, 0, 0, 0);
            ac3 = __builtin_amdgcn_mfma_f32_16x16x32_f16(a[kt + 3], wf[kt + 3], ac3, 0, 0, 0);
        }
        f32x4 s = (ac0 + ac1) + (ac2 + ac3);

        // D: lane(c,q) reg r -> batch g*16+q*4+r, col n0+c
#pragma unroll
        for (int r = 0; r < 4; ++r)
            hsp[(size_t)r * DS] = (half_t)fast_tanh(s[r] + pvc[r]);

        __syncthreads();                   // vmcnt(0) drain + barrier
        if (t == 0)
            __hip_atomic_store(&fl[myf], (uint32_t)(l + 1),
                               __ATOMIC_RELEASE, __HIP_MEMORY_SCOPE_AGENT);

        hsp += (size_t)B_ * DS;
        ap  += (size_t)B_ * DS;
#pragma unroll
        for (int r = 0; r < 4; ++r) pvc[r] = pvn[r];
    }
}

// ---------------------------------------------------------------- kernel C
// y[r][o] = tanh(sum_s hs[r][s]*W_fc[o][s] + b_fc[o]),  r = l*B+b
__global__ __launch_bounds__(256) void rnn_out_kernel(
    const half_t* __restrict__ hs, const float* __restrict__ Wfc,
    const float* __restrict__ bfc, float* __restrict__ y)
{
    __shared__ half_t Hs[64 * 72];     // [r][k], stride 72
    __shared__ half_t Ws[128 * 72];    // [o][k], stride 72
    const int t  = threadIdx.x;
    const int r0 = blockIdx.x * 64;

    const int lb = (t >> 4) * 4;
    const int ob = (t & 15) * 8;
    float acc[4][8];
#pragma unroll
    for (int i = 0; i < 4; ++i)
#pragma unroll
        for (int j = 0; j < 8; ++j) acc[i][j] = 0.f;

    for (int kc = 0; kc < DS; kc += 64) {
#pragma unroll
        for (int i = 0; i < 2; ++i) {
            int u = i * 256 + t;
            int r = u >> 3, c8 = u & 7;
            uint4 v = ((const uint4*)(hs + (size_t)(r0 + r) * DS + kc))[c8];
            *(uint4*)&Hs[r * 72 + c8 * 8] = v;
        }
#pragma unroll
        for (int i = 0; i < 8; ++i) {
            int u = i * 256 + t;
            int o = u >> 4, c4 = u & 15;
            float4 wv = *(const float4*)&Wfc[(size_t)o * DS + kc + c4 * 4];
            half4_t hw = {(half_t)wv.x, (half_t)wv.y, (half_t)wv.z, (half_t)wv.w};
            *(half4_t*)&Ws[o * 72 + c4 * 4] = hw;
        }
        __syncthreads();
#pragma unroll
        for (int k8 = 0; k8 < 64; k8 += 8) {
            uint4 xa[4], wb[8];
#pragma unroll
            for (int i = 0; i < 4; ++i) xa[i] = *(const uint4*)&Hs[(lb + i) * 72 + k8];
#pragma unroll
            for (int j = 0; j < 8; ++j) wb[j] = *(const uint4*)&Ws[(ob + j) * 72 + k8];
#pragma unroll
            for (int i = 0; i < 4; ++i)
#pragma unroll
                for (int j = 0; j < 8; ++j) {
                    float a = acc[i][j];
                    a = fd2(xa[i].x, wb[j].x, a);
                    a = fd2(xa[i].y, wb[j].y, a);
                    a = fd2(xa[i].z, wb[j].z, a);
                    a = fd2(xa[i].w, wb[j].w, a);
                    acc[i][j] = a;
                }
        }
        __syncthreads();
    }

#pragma unroll
    for (int i = 0; i < 4; ++i) {
        float4 r0v = {fast_tanh(acc[i][0] + bfc[ob + 0]), fast_tanh(acc[i][1] + bfc[ob + 1]),
                      fast_tanh(acc[i][2] + bfc[ob + 2]), fast_tanh(acc[i][3] + bfc[ob + 3])};
        float4 r1v = {fast_tanh(acc[i][4] + bfc[ob + 4]), fast_tanh(acc[i][5] + bfc[ob + 5]),
                      fast_tanh(acc[i][6] + bfc[ob + 6]), fast_tanh(acc[i][7] + bfc[ob + 7])};
        float* yr = y + (size_t)(r0 + lb + i) * DIN + ob;
        *(float4*)yr       = r0v;
        *((float4*)yr + 1) = r1v;
    }
}

// ---------------------------------------------------------------- launch
extern "C" void kernel_launch(void* const* d_in, const int* in_sizes, int n_in,
                              void* d_out, int out_size, void* d_ws, size_t ws_size,
                              hipStream_t stream) {
    (void)in_sizes; (void)n_in; (void)ws_size;
    const float* x   = (const float*)d_in[0];
    const float* Wih = (const float*)d_in[1];
    const float* Whh = (const float*)d_in[2];
    const float* bih = (const float*)d_in[3];
    const float* bhh = (const float*)d_in[4];
    const float* Wfc = (const float*)d_in[5];
    const float* bfc = (const float*)d_in[6];
    float* y = (float*)d_out;

    half_t* pre = (half_t*)d_ws;                                        // pre[b][l][h]: 64 MB
    half_t* hs  = (half_t*)((char*)d_ws + (size_t)B_ * LEN * DS * 2);   // hs[(l*B+b)][s]: 64 MB

    // Sync flags live in the TAIL of d_out (4 KB). Safe: zeroed by the pre
    // kernel, used by recur, then kernel C overwrites all of d_out with y.
    uint32_t* flags = (uint32_t*)((char*)d_out + (size_t)out_size - FLAGS_BYTES);

    rnn_pre_kernel<<<dim3(LEN / 64, B_, DS / 128), 256, 0, stream>>>(x, Wih, bih, bhh, pre, flags);
    rnn_recur_kernel<<<dim3(64), 256, 0, stream>>>(Whh, pre, hs, flags);
    rnn_out_kernel<<<dim3(LEN * B_ / 64), 256, 0, stream>>>(hs, Wfc, bfc, y);
}

// Round 5
// 3409.280 us; speedup vs baseline: 4.8527x; 4.8527x over previous
//
#include <hip/hip_runtime.h>
#include <cstdint>

typedef _Float16 half_t;
typedef __attribute__((ext_vector_type(2))) _Float16 half2_t;
typedef __attribute__((ext_vector_type(4))) _Float16 half4_t;
typedef __attribute__((ext_vector_type(8))) _Float16 half8_t;
typedef __attribute__((ext_vector_type(4))) float f32x4;

#define B_    32
#define DIN   128
#define LEN   2048
#define DS    512
#define NKT   16                            // K-tiles of 32 (16x16x32 MFMA)
#define KTR   12                            // logical tiles j=0..11 in registers
#define KTL   (NKT - KTR)                   // logical tiles j=12..15 in LDS
#define LDSB_BYTES (KTL * 32 * 1024)        // 4 x 32 x 1KB = 131072
#define HBUF_OFF   LDSB_BYTES
#define LDS_BYTES  (LDSB_BYTES + 2 * DS * 2)   // + h ping-pong = 133120 < 160K

__device__ __forceinline__ float fast_tanh(float x) {
    float e = __expf(2.0f * x);        // large |x| saturates correctly via inf/0
    return 1.0f - 2.0f / (e + 1.0f);
}

__device__ __forceinline__ float fd2(uint32_t a, uint32_t b, float c) {
    return __builtin_amdgcn_fdot2(__builtin_bit_cast(half2_t, a),
                                  __builtin_bit_cast(half2_t, b), c, false);
}

// B-fragment for 16x16x32: lane(c=lane&15, q=lane>>4) holds B[k0+q*8+j][n0+c]
// = W[n0+c][k0+q*8+j], j=0..7 -> 8 consecutive f32 from W row n0+c.
__device__ __forceinline__ half8_t load_wfrag(const float* __restrict__ W,
                                              int n0, int c, int q, int kt) {
    const float* p = W + (size_t)(n0 + c) * DS + kt * 32 + q * 8;
    float4 f0 = *(const float4*)p;
    float4 f1 = *(const float4*)(p + 4);
    half8_t r = {(half_t)f0.x, (half_t)f0.y, (half_t)f0.z, (half_t)f0.w,
                 (half_t)f1.x, (half_t)f1.y, (half_t)f1.z, (half_t)f1.w};
    return r;
}

// ---------------------------------------------------------------- kernel A
// pre[b][l][h] = sum_d x[b][d][l]*W_ih[h][d] + b_ih[h] + b_hh[h]   (f16 out)
__global__ __launch_bounds__(256) void rnn_pre_kernel(
    const float* __restrict__ x, const float* __restrict__ Wih,
    const float* __restrict__ bih, const float* __restrict__ bhh,
    half_t* __restrict__ pre)
{
    __shared__ half_t Xs[64 * 136];    // [l][d], stride 136
    __shared__ half_t Ws[128 * 136];   // [h][d], stride 136
    const int t  = threadIdx.x;
    const int l0 = blockIdx.x * 64;
    const int b  = blockIdx.y;
    const int h0 = blockIdx.z * 128;

#pragma unroll
    for (int i = 0; i < 32; ++i) {
        int idx = i * 256 + t;
        int j = idx & 63, d = idx >> 6;
        Xs[j * 136 + d] = (half_t)x[(size_t)b * DIN * LEN + (size_t)d * LEN + l0 + j];
    }
#pragma unroll
    for (int i = 0; i < 16; ++i) {
        int f4 = i * 256 + t;
        int h = f4 >> 5, d4 = f4 & 31;
        float4 w = *(const float4*)&Wih[(size_t)(h0 + h) * DIN + d4 * 4];
        half4_t hw = {(half_t)w.x, (half_t)w.y, (half_t)w.z, (half_t)w.w};
        *(half4_t*)&Ws[h * 136 + d4 * 4] = hw;
    }
    __syncthreads();

    const int lb = (t >> 4) * 4;
    const int hb = (t & 15) * 8;
    float acc[4][8];
#pragma unroll
    for (int i = 0; i < 4; ++i)
#pragma unroll
        for (int j = 0; j < 8; ++j) acc[i][j] = 0.f;

    for (int kc = 0; kc < DIN; kc += 8) {
        uint4 xa[4], wb[8];
#pragma unroll
        for (int i = 0; i < 4; ++i) xa[i] = *(const uint4*)&Xs[(lb + i) * 136 + kc];
#pragma unroll
        for (int j = 0; j < 8; ++j) wb[j] = *(const uint4*)&Ws[(hb + j) * 136 + kc];
#pragma unroll
        for (int i = 0; i < 4; ++i)
#pragma unroll
            for (int j = 0; j < 8; ++j) {
                float a = acc[i][j];
                a = fd2(xa[i].x, wb[j].x, a);
                a = fd2(xa[i].y, wb[j].y, a);
                a = fd2(xa[i].z, wb[j].z, a);
                a = fd2(xa[i].w, wb[j].w, a);
                acc[i][j] = a;
            }
    }

    float bias[8];
#pragma unroll
    for (int j = 0; j < 8; ++j) bias[j] = bih[h0 + hb + j] + bhh[h0 + hb + j];
#pragma unroll
    for (int i = 0; i < 4; ++i) {
        half8_t s;
#pragma unroll
        for (int j = 0; j < 8; ++j) s[j] = (half_t)(acc[i][j] + bias[j]);
        *(half8_t*)&pre[((size_t)b * LEN + l0 + lb + i) * DS + h0 + hb] = s;
    }
}

// ---------------------------------------------------------------- kernel B
// MFMA scan: one block per batch. Wave w owns outputs n in [w*64, w*64+64)
// as 4 16-wide N-tiles. h_t replicated across M via A-operand (M=1 real).
// All 16 D-rows identical: lane (c,q) holds column n0w+q*16+c in acc[q].x --
// exactly the column whose pre value this lane loaded.
//
// Per-wave K-ROTATION: logical tile j <-> physical kt = (2w+j)&15, so each
// wave's OWN k-tiles (the h columns it itself computes, kt=2w,2w+1) are
// always j=0,1 (register-resident, compile-time indices). At the step tail,
// after writing its h slice to LDS, the wave reads back its own 128B (no
// barrier needed -- own data) and issues the 8 j=0,1 MFMAs for the NEXT
// step BEFORE s_barrier, overlapping them with barrier wait + other waves'
// tails. Body covers j=2..15 with carried accumulators.
// j=0..11 from breg; j=12..15 from per-wave LDS regions (written at init).
// Barrier is lgkm-only (global stores / pre prefetch stay in flight).
__global__ __launch_bounds__(512) __attribute__((amdgpu_waves_per_eu(2, 2)))
void rnn_recur_kernel(
    const float* __restrict__ Whh, const half_t* __restrict__ pre,
    half_t* __restrict__ hs)
{
    extern __shared__ char smem[];
    const int t    = threadIdx.x;
    const int b    = blockIdx.x;
    const int w    = t >> 6;
    const int lane = t & 63;
    const int c    = lane & 15;
    const int q    = lane >> 4;
    const int n0w  = w * 64;

    // --- register-resident B-fragments for logical j=0..11 (physical (2w+j)&15)
    half8_t breg[KTR][4];
#pragma unroll
    for (int j = 0; j < KTR; ++j)
#pragma unroll
        for (int nt = 0; nt < 4; ++nt)
            breg[j][nt] = load_wfrag(Whh, n0w + nt * 16, c, q, (2 * w + j) & 15);

    // --- LDS-resident B-fragments for logical j=12..15, per-wave region
#pragma unroll
    for (int j = KTR; j < NKT; ++j)
#pragma unroll
        for (int nt = 0; nt < 4; ++nt) {
            half8_t f = load_wfrag(Whh, n0w + nt * 16, c, q, (2 * w + j) & 15);
            int slot = (j - KTR) * 32 + w * 4 + nt;
            *(half8_t*)(smem + (slot << 10) + lane * 16) = f;
        }
    if (t < DS) *(half_t*)(smem + HBUF_OFF + t * 2) = (half_t)0.f;  // h_{-1}=0
    __syncthreads();

    const half_t* prew = pre + (size_t)b * LEN * DS + n0w + lane;  // lane j -> n0w+j
    float pv0 = (float)prew[0];            // pre value, step l
    float pv1 = (float)prew[DS];           // step l+1 (prefetch distance 2)
    const half_t* pw2 = prew + 2 * (size_t)DS;   // incrementing ptr for step l+2
    half_t* hw = hs + (size_t)b * DS;            // incrementing hs row ptr

    const int wq16 = w * 128 + q * 16;     // own-tile A-frag base (j=0)

    // accumulators carried across iterations (tail j=0,1 of NEXT step)
    f32x4 acc0 = {0.f, 0.f, 0.f, 0.f};
    f32x4 acc1 = {0.f, 0.f, 0.f, 0.f};
    f32x4 acc2 = {0.f, 0.f, 0.f, 0.f};
    f32x4 acc3 = {0.f, 0.f, 0.f, 0.f};

    int par = 0;
    for (int l = 0; l < LEN; ++l) {
        float pv2 = (float)*pw2;                                   // prefetch l+2
        if (l < LEN - 3) pw2 += DS;                                // clamp at last row

        const char* hb = smem + HBUF_OFF + par * 1024;
        // body: logical j = 2..15 (physical (2w+j)&15); A-frag byte offset
        // within the 1KB h buffer is (w*128 + j*64) mod 1024, + q*16.
#pragma unroll
        for (int j = 2; j < KTR; ++j) {
            int off = (w * 128 + j * 64) & 1023;                   // uniform SALU
            half8_t a = *(const half8_t*)(hb + off + q * 16);      // 4-addr multicast
            acc0 = __builtin_amdgcn_mfma_f32_16x16x32_f16(a, breg[j][0], acc0, 0, 0, 0);
            acc1 = __builtin_amdgcn_mfma_f32_16x16x32_f16(a, breg[j][1], acc1, 0, 0, 0);
            acc2 = __builtin_amdgcn_mfma_f32_16x16x32_f16(a, breg[j][2], acc2, 0, 0, 0);
            acc3 = __builtin_amdgcn_mfma_f32_16x16x32_f16(a, breg[j][3], acc3, 0, 0, 0);
        }
#pragma unroll
        for (int j = KTR; j < NKT; ++j) {
            int off = (w * 128 + j * 64) & 1023;
            half8_t a = *(const half8_t*)(hb + off + q * 16);
            const char* bb = smem + (((j - KTR) * 32 + w * 4) << 10) + lane * 16;
            half8_t b0 = *(const half8_t*)(bb);
            half8_t b1 = *(const half8_t*)(bb + 1024);
            half8_t b2 = *(const half8_t*)(bb + 2048);
            half8_t b3 = *(const half8_t*)(bb + 3072);
            acc0 = __builtin_amdgcn_mfma_f32_16x16x32_f16(a, b0, acc0, 0, 0, 0);
            acc1 = __builtin_amdgcn_mfma_f32_16x16x32_f16(a, b1, acc1, 0, 0, 0);
            acc2 = __builtin_amdgcn_mfma_f32_16x16x32_f16(a, b2, acc2, 0, 0, 0);
            acc3 = __builtin_amdgcn_mfma_f32_16x16x32_f16(a, b3, acc3, 0, 0, 0);
        }

        // D rows all identical -> lane (c,q) has column n0w+q*16+c in acc[q].x,
        // matching this lane's own pv (prew + lane). Select acc by q (cndmask).
        float a01 = (q & 1) ? acc1.x : acc0.x;
        float a23 = (q & 1) ? acc3.x : acc2.x;
        float av  = (q & 2) ? a23 : a01;
        half_t hv = (half_t)fast_tanh(pv0 + av);

        char* hn = smem + HBUF_OFF + (par ^ 1) * 1024;
        *(half_t*)(hn + (n0w + lane) * 2) = hv;            // 128B/wave, conflict-free
        hw[n0w + lane] = hv;                               // coalesced 128B/wave
        hw += B_ * DS;

        // reset accumulators; tail pre-computes j=0,1 of the NEXT step from
        // this wave's OWN just-written h slice (no barrier dependency).
        acc0 = (f32x4){0.f, 0.f, 0.f, 0.f};
        acc1 = (f32x4){0.f, 0.f, 0.f, 0.f};
        acc2 = (f32x4){0.f, 0.f, 0.f, 0.f};
        acc3 = (f32x4){0.f, 0.f, 0.f, 0.f};
        if (l != LEN - 1) {                                // wave-uniform branch
            half8_t a0 = *(const half8_t*)(hn + wq16);         // j=0 (kt=2w)
            half8_t a1 = *(const half8_t*)(hn + wq16 + 64);    // j=1 (kt=2w+1)
            acc0 = __builtin_amdgcn_mfma_f32_16x16x32_f16(a0, breg[0][0], acc0, 0, 0, 0);
            acc1 = __builtin_amdgcn_mfma_f32_16x16x32_f16(a0, breg[0][1], acc1, 0, 0, 0);
            acc2 = __builtin_amdgcn_mfma_f32_16x16x32_f16(a0, breg[0][2], acc2, 0, 0, 0);
            acc3 = __builtin_amdgcn_mfma_f32_16x16x32_f16(a0, breg[0][3], acc3, 0, 0, 0);
            acc0 = __builtin_amdgcn_mfma_f32_16x16x32_f16(a1, breg[1][0], acc0, 0, 0, 0);
            acc1 = __builtin_amdgcn_mfma_f32_16x16x32_f16(a1, breg[1][1], acc1, 0, 0, 0);
            acc2 = __builtin_amdgcn_mfma_f32_16x16x32_f16(a1, breg[1][2], acc2, 0, 0, 0);
            acc3 = __builtin_amdgcn_mfma_f32_16x16x32_f16(a1, breg[1][3], acc3, 0, 0, 0);
            __builtin_amdgcn_sched_barrier(0);             // keep tail MFMAs here
        }

        pv0 = pv1;
        pv1 = pv2;
        par ^= 1;
        // LDS-only barrier: do NOT drain vmcnt (stores / pre prefetch stay
        // in flight across the barrier)
        asm volatile("s_waitcnt lgkmcnt(0)\n\ts_barrier" ::: "memory");
    }
}

// ---------------------------------------------------------------- kernel C
// y[r][o] = tanh(sum_s hs[r][s]*W_fc[o][s] + b_fc[o]),  r = l*B+b
__global__ __launch_bounds__(256) void rnn_out_kernel(
    const half_t* __restrict__ hs, const float* __restrict__ Wfc,
    const float* __restrict__ bfc, float* __restrict__ y)
{
    __shared__ half_t Hs[64 * 72];     // [r][k], stride 72
    __shared__ half_t Ws[128 * 72];    // [o][k], stride 72
    const int t  = threadIdx.x;
    const int r0 = blockIdx.x * 64;

    const int lb = (t >> 4) * 4;
    const int ob = (t & 15) * 8;
    float acc[4][8];
#pragma unroll
    for (int i = 0; i < 4; ++i)
#pragma unroll
        for (int j = 0; j < 8; ++j) acc[i][j] = 0.f;

    for (int kc = 0; kc < DS; kc += 64) {
#pragma unroll
        for (int i = 0; i < 2; ++i) {
            int u = i * 256 + t;
            int r = u >> 3, c8 = u & 7;
            uint4 v = ((const uint4*)(hs + (size_t)(r0 + r) * DS + kc))[c8];
            *(uint4*)&Hs[r * 72 + c8 * 8] = v;
        }
#pragma unroll
        for (int i = 0; i < 8; ++i) {
            int u = i * 256 + t;
            int o = u >> 4, c4 = u & 15;
            float4 wv = *(const float4*)&Wfc[(size_t)o * DS + kc + c4 * 4];
            half4_t hw = {(half_t)wv.x, (half_t)wv.y, (half_t)wv.z, (half_t)wv.w};
            *(half4_t*)&Ws[o * 72 + c4 * 4] = hw;
        }
        __syncthreads();
#pragma unroll
        for (int k8 = 0; k8 < 64; k8 += 8) {
            uint4 xa[4], wb[8];
#pragma unroll
            for (int i = 0; i < 4; ++i) xa[i] = *(const uint4*)&Hs[(lb + i) * 72 + k8];
#pragma unroll
            for (int j = 0; j < 8; ++j) wb[j] = *(const uint4*)&Ws[(ob + j) * 72 + k8];
#pragma unroll
            for (int i = 0; i < 4; ++i)
#pragma unroll
                for (int j = 0; j < 8; ++j) {
                    float a = acc[i][j];
                    a = fd2(xa[i].x, wb[j].x, a);
                    a = fd2(xa[i].y, wb[j].y, a);
                    a = fd2(xa[i].z, wb[j].z, a);
                    a = fd2(xa[i].w, wb[j].w, a);
                    acc[i][j] = a;
                }
        }
        __syncthreads();
    }

#pragma unroll
    for (int i = 0; i < 4; ++i) {
        float4 r0v = {fast_tanh(acc[i][0] + bfc[ob + 0]), fast_tanh(acc[i][1] + bfc[ob + 1]),
                      fast_tanh(acc[i][2] + bfc[ob + 2]), fast_tanh(acc[i][3] + bfc[ob + 3])};
        float4 r1v = {fast_tanh(acc[i][4] + bfc[ob + 4]), fast_tanh(acc[i][5] + bfc[ob + 5]),
                      fast_tanh(acc[i][6] + bfc[ob + 6]), fast_tanh(acc[i][7] + bfc[ob + 7])};
        float* yr = y + (size_t)(r0 + lb + i) * DIN + ob;
        *(float4*)yr       = r0v;
        *((float4*)yr + 1) = r1v;
    }
}

// ---------------------------------------------------------------- launch
extern "C" void kernel_launch(void* const* d_in, const int* in_sizes, int n_in,
                              void* d_out, int out_size, void* d_ws, size_t ws_size,
                              hipStream_t stream) {
    (void)in_sizes; (void)n_in; (void)out_size; (void)ws_size;
    const float* x   = (const float*)d_in[0];
    const float* Wih = (const float*)d_in[1];
    const float* Whh = (const float*)d_in[2];
    const float* bih = (const float*)d_in[3];
    const float* bhh = (const float*)d_in[4];
    const float* Wfc = (const float*)d_in[5];
    const float* bfc = (const float*)d_in[6];
    float* y = (float*)d_out;

    half_t* pre = (half_t*)d_ws;                                        // pre[b][l][h]: 64 MB
    half_t* hs  = (half_t*)((char*)d_ws + (size_t)B_ * LEN * DS * 2);   // hs[(l*B+b)][s]: 64 MB

    hipFuncSetAttribute((const void*)rnn_recur_kernel,
                        hipFuncAttributeMaxDynamicSharedMemorySize, LDS_BYTES);

    rnn_pre_kernel<<<dim3(LEN / 64, B_, DS / 128), 256, 0, stream>>>(x, Wih, bih, bhh, pre);
    rnn_recur_kernel<<<dim3(B_), 512, LDS_BYTES, stream>>>(Whh, pre, hs);
    rnn_out_kernel<<<dim3(LEN * B_ / 64), 256, 0, stream>>>(hs, Wfc, bfc, y);
}

// Round 7
// 2764.880 us; speedup vs baseline: 5.9837x; 1.2331x over previous
//
#include <hip/hip_runtime.h>
#include <cstdint>

typedef _Float16 half_t;
typedef __attribute__((ext_vector_type(2))) _Float16 half2_t;
typedef __attribute__((ext_vector_type(4))) _Float16 half4_t;
typedef __attribute__((ext_vector_type(8))) _Float16 half8_t;
typedef __attribute__((ext_vector_type(4))) float f32x4;

#define B_    32
#define DIN   128
#define LEN   2048
#define DS    512
#define NKT   16                            // K-tiles of 32 (16x16x32 MFMA)
#define KTR   12                            // K-tiles resident in registers/AGPRs
#define KTL   (NKT - KTR)                   // K-tiles streamed from LDS
#define LDSB_BYTES (KTL * 32 * 1024)        // 4 kt x 32 ntiles x 1KB = 131072
#define HBUF_OFF   LDSB_BYTES
#define LDS_BYTES  (LDSB_BYTES + 2 * DS * 2)   // + h ping-pong = 133120 < 160K

__device__ __forceinline__ float fast_tanh(float x) {
    float e = __expf(2.0f * x);        // large |x| saturates correctly via inf/0
    return 1.0f - 2.0f / (e + 1.0f);
}

// B-fragment for 16x16x32: lane(c=lane&15, q=lane>>4) holds B[k0+q*8+j][n0+c]
// = W[n0+c][k0+q*8+j], j=0..7 -> 8 consecutive f32 from W row n0+c.
__device__ __forceinline__ half8_t load_wfrag(const float* __restrict__ W,
                                              int n0, int c, int q, int kt) {
    const float* p = W + (size_t)(n0 + c) * DS + kt * 32 + q * 8;
    float4 f0 = *(const float4*)p;
    float4 f1 = *(const float4*)(p + 4);
    half8_t r = {(half_t)f0.x, (half_t)f0.y, (half_t)f0.z, (half_t)f0.w,
                 (half_t)f1.x, (half_t)f1.y, (half_t)f1.z, (half_t)f1.w};
    return r;
}

// ---------------------------------------------------------------- kernel A
// pre[b][l][h] = sum_d x[b][d][l]*W_ih[h][d] + b_ih[h] + b_hh[h]   (f16 out)
// MFMA version: D[h][l] = W_ih(MxK) x Xs^T(KxN).  M=h (8 tiles), N=l (4
// tiles), K=DIN=128 (4 kt).  Wave w owns M-tiles {2w, 2w+1} x all N.
// Operand-swapped so D rows (q*4+reg) = 4 consecutive h -> half4 stores.
__global__ __launch_bounds__(256) void rnn_pre_kernel(
    const float* __restrict__ x, const float* __restrict__ Wih,
    const float* __restrict__ bih, const float* __restrict__ bhh,
    half_t* __restrict__ pre)
{
    __shared__ half_t Xs[64 * 136];    // [l][d], stride 136 (272B, 16B-mult)
    __shared__ half_t Ws[128 * 136];   // [h][d], stride 136
    const int t  = threadIdx.x;
    const int l0 = blockIdx.x * 64;
    const int b  = blockIdx.y;
    const int h0 = blockIdx.z * 128;

#pragma unroll
    for (int i = 0; i < 32; ++i) {
        int idx = i * 256 + t;
        int j = idx & 63, d = idx >> 6;
        Xs[j * 136 + d] = (half_t)x[(size_t)b * DIN * LEN + (size_t)d * LEN + l0 + j];
    }
#pragma unroll
    for (int i = 0; i < 16; ++i) {
        int f4 = i * 256 + t;
        int h = f4 >> 5, d4 = f4 & 31;
        float4 w = *(const float4*)&Wih[(size_t)(h0 + h) * DIN + d4 * 4];
        half4_t hw = {(half_t)w.x, (half_t)w.y, (half_t)w.z, (half_t)w.w};
        *(half4_t*)&Ws[h * 136 + d4 * 4] = hw;
    }
    __syncthreads();

    const int w    = t >> 6;
    const int lane = t & 63;
    const int c    = lane & 15;
    const int q    = lane >> 4;

    f32x4 acc[2][4];
#pragma unroll
    for (int mt = 0; mt < 2; ++mt)
#pragma unroll
        for (int nt = 0; nt < 4; ++nt) acc[mt][nt] = (f32x4){0.f, 0.f, 0.f, 0.f};

#pragma unroll
    for (int kt = 0; kt < 4; ++kt) {
        // A-frags: lane(c,q) = Wih_f16[(m0+c)][kt*32+q*8 ..+8]
        half8_t a0 = *(const half8_t*)&Ws[((w * 2 + 0) * 16 + c) * 136 + kt * 32 + q * 8];
        half8_t a1 = *(const half8_t*)&Ws[((w * 2 + 1) * 16 + c) * 136 + kt * 32 + q * 8];
#pragma unroll
        for (int nt = 0; nt < 4; ++nt) {
            // B-frag: lane(c,q) = B[k][n0+c] = Xs[(n0+c)][k]
            half8_t bx = *(const half8_t*)&Xs[(nt * 16 + c) * 136 + kt * 32 + q * 8];
            acc[0][nt] = __builtin_amdgcn_mfma_f32_16x16x32_f16(a0, bx, acc[0][nt], 0, 0, 0);
            acc[1][nt] = __builtin_amdgcn_mfma_f32_16x16x32_f16(a1, bx, acc[1][nt], 0, 0, 0);
        }
    }

    // D: lane(c,q) reg r -> h = m0 + q*4 + r, l = n0 + c
#pragma unroll
    for (int mt = 0; mt < 2; ++mt) {
        const int hbase = h0 + (w * 2 + mt) * 16 + q * 4;
        float4 bi = *(const float4*)&bih[hbase];
        float4 bh = *(const float4*)&bhh[hbase];
        float b0 = bi.x + bh.x, b1 = bi.y + bh.y, b2 = bi.z + bh.z, b3 = bi.w + bh.w;
#pragma unroll
        for (int nt = 0; nt < 4; ++nt) {
            half4_t s = {(half_t)(acc[mt][nt].x + b0), (half_t)(acc[mt][nt].y + b1),
                         (half_t)(acc[mt][nt].z + b2), (half_t)(acc[mt][nt].w + b3)};
            *(half4_t*)&pre[((size_t)b * LEN + l0 + nt * 16 + c) * DS + hbase] = s;
        }
    }
}

// ---------------------------------------------------------------- kernel B
// MFMA scan (r1-verified structure, 2630us): one block per batch. Wave w
// owns outputs n in [w*64, w*64+64) as 4 16-wide N-tiles. h_t replicated
// across M via A-operand (M=1 real). All 16 D-rows identical: lane (c,q)
// holds column n0w+q*16+c in acc[q].x -- exactly the column whose pre value
// this lane loaded. Barrier is lgkm-only (global stores / pre prefetch stay
// in flight across it).
__global__ __launch_bounds__(512) __attribute__((amdgpu_waves_per_eu(2, 2)))
void rnn_recur_kernel(
    const float* __restrict__ Whh, const half_t* __restrict__ pre,
    half_t* __restrict__ hs)
{
    extern __shared__ char smem[];
    const int t    = threadIdx.x;
    const int b    = blockIdx.x;
    const int w    = t >> 6;
    const int lane = t & 63;
    const int c    = lane & 15;
    const int q    = lane >> 4;
    const int n0w  = w * 64;

    // --- register-resident B-fragments (48 x half8 = 192 regs; MFMA-only use)
    half8_t breg[KTR][4];
#pragma unroll
    for (int kt = 0; kt < KTR; ++kt)
#pragma unroll
        for (int nt = 0; nt < 4; ++nt)
            breg[kt][nt] = load_wfrag(Whh, n0w + nt * 16, c, q, kt);

    // --- LDS-resident B-fragments, frag-linear: [(kt-KTR)*32+gid][lane*16B]
#pragma unroll
    for (int kt = KTR; kt < NKT; ++kt)
#pragma unroll
        for (int nt = 0; nt < 4; ++nt) {
            half8_t f = load_wfrag(Whh, n0w + nt * 16, c, q, kt);
            int gid = w * 4 + nt;
            *(half8_t*)(smem + (((kt - KTR) * 32 + gid) << 10) + lane * 16) = f;
        }
    if (t < DS) *(half_t*)(smem + HBUF_OFF + t * 2) = (half_t)0.f;  // h_{-1}=0
    __syncthreads();

    const half_t* prew = pre + (size_t)b * LEN * DS + n0w + lane;  // lane j -> n0w+j
    half_t* hsb = hs + (size_t)b * DS;
    float pv0 = (float)prew[0];            // pre value for this lane's column, step l
    float pv1 = (float)prew[DS];           // step l+1 (prefetch distance 2)

    int par = 0;
    for (int l = 0; l < LEN; ++l) {
        int l2 = (l + 2 < LEN) ? (l + 2) : (LEN - 1);
        float pv2 = (float)prew[(size_t)l2 * DS];                  // prefetch l+2

        const char* hb = smem + HBUF_OFF + par * 1024;
        f32x4 acc0 = {0.f, 0.f, 0.f, 0.f};
        f32x4 acc1 = {0.f, 0.f, 0.f, 0.f};
        f32x4 acc2 = {0.f, 0.f, 0.f, 0.f};
        f32x4 acc3 = {0.f, 0.f, 0.f, 0.f};
#pragma unroll
        for (int kt = 0; kt < KTR; ++kt) {
            half8_t a = *(const half8_t*)(hb + kt * 64 + q * 16);  // 4-addr multicast
            acc0 = __builtin_amdgcn_mfma_f32_16x16x32_f16(a, breg[kt][0], acc0, 0, 0, 0);
            acc1 = __builtin_amdgcn_mfma_f32_16x16x32_f16(a, breg[kt][1], acc1, 0, 0, 0);
            acc2 = __builtin_amdgcn_mfma_f32_16x16x32_f16(a, breg[kt][2], acc2, 0, 0, 0);
            acc3 = __builtin_amdgcn_mfma_f32_16x16x32_f16(a, breg[kt][3], acc3, 0, 0, 0);
        }
#pragma unroll
        for (int kt = KTR; kt < NKT; ++kt) {
            half8_t a = *(const half8_t*)(hb + kt * 64 + q * 16);
            const char* bb = smem + (((kt - KTR) * 32 + w * 4) << 10) + lane * 16;
            half8_t b0 = *(const half8_t*)(bb);
            half8_t b1 = *(const half8_t*)(bb + 1024);
            half8_t b2 = *(const half8_t*)(bb + 2048);
            half8_t b3 = *(const half8_t*)(bb + 3072);
            acc0 = __builtin_amdgcn_mfma_f32_16x16x32_f16(a, b0, acc0, 0, 0, 0);
            acc1 = __builtin_amdgcn_mfma_f32_16x16x32_f16(a, b1, acc1, 0, 0, 0);
            acc2 = __builtin_amdgcn_mfma_f32_16x16x32_f16(a, b2, acc2, 0, 0, 0);
            acc3 = __builtin_amdgcn_mfma_f32_16x16x32_f16(a, b3, acc3, 0, 0, 0);
        }

        // D rows all identical -> lane (c,q) has column n0w+q*16+c in acc[q].x,
        // matching this lane's own pv (prew + lane). Select acc by q (cndmask).
        float a01 = (q & 1) ? acc1.x : acc0.x;
        float a23 = (q & 1) ? acc3.x : acc2.x;
        float av  = (q & 2) ? a23 : a01;
        half_t hv = (half_t)fast_tanh(pv0 + av);

        char* hn = smem + HBUF_OFF + (par ^ 1) * 1024;
        *(half_t*)(hn + (n0w + lane) * 2) = hv;            // 128B/wave, conflict-free
        hsb[(size_t)l * (B_ * DS) + n0w + lane] = hv;      // coalesced 128B/wave

        pv0 = pv1;
        pv1 = pv2;
        par ^= 1;
        // LDS-only barrier: do NOT drain vmcnt (stores/prefetch stay in flight)
        asm volatile("s_waitcnt lgkmcnt(0)\n\ts_barrier" ::: "memory");
    }
}

// ---------------------------------------------------------------- kernel C
// y[r][o] = tanh(sum_s hs[r][s]*W_fc[o][s] + b_fc[o]),  r = l*B+b
// MFMA version: D[o][r] = Wfc(MxK) x Hs^T(KxN).  M=o (8 tiles), N=r (4
// tiles), K=DS=512 as 8 chunks of 64 (2 kt each).  Wave w owns M-tiles
// {2w, 2w+1} x all N.  D rows (q*4+reg) = 4 consecutive o -> float4 stores.
__global__ __launch_bounds__(256) void rnn_out_kernel(
    const half_t* __restrict__ hs, const float* __restrict__ Wfc,
    const float* __restrict__ bfc, float* __restrict__ y)
{
    __shared__ half_t Hs[64 * 72];     // [r][k], stride 72 (144B, 16B-mult)
    __shared__ half_t Ws[128 * 72];    // [o][k], stride 72
    const int t  = threadIdx.x;
    const int r0 = blockIdx.x * 64;

    const int w    = t >> 6;
    const int lane = t & 63;
    const int c    = lane & 15;
    const int q    = lane >> 4;

    f32x4 acc[2][4];
#pragma unroll
    for (int mt = 0; mt < 2; ++mt)
#pragma unroll
        for (int nt = 0; nt < 4; ++nt) acc[mt][nt] = (f32x4){0.f, 0.f, 0.f, 0.f};

    for (int kc = 0; kc < DS; kc += 64) {
#pragma unroll
        for (int i = 0; i < 2; ++i) {
            int u = i * 256 + t;
            int r = u >> 3, c8 = u & 7;
            uint4 v = ((const uint4*)(hs + (size_t)(r0 + r) * DS + kc))[c8];
            *(uint4*)&Hs[r * 72 + c8 * 8] = v;
        }
#pragma unroll
        for (int i = 0; i < 8; ++i) {
            int u = i * 256 + t;
            int o = u >> 4, c4 = u & 15;
            float4 wv = *(const float4*)&Wfc[(size_t)o * DS + kc + c4 * 4];
            half4_t hw = {(half_t)wv.x, (half_t)wv.y, (half_t)wv.z, (half_t)wv.w};
            *(half4_t*)&Ws[o * 72 + c4 * 4] = hw;
        }
        __syncthreads();
#pragma unroll
        for (int kt = 0; kt < 2; ++kt) {
            half8_t a0 = *(const half8_t*)&Ws[((w * 2 + 0) * 16 + c) * 72 + kt * 32 + q * 8];
            half8_t a1 = *(const half8_t*)&Ws[((w * 2 + 1) * 16 + c) * 72 + kt * 32 + q * 8];
#pragma unroll
            for (int nt = 0; nt < 4; ++nt) {
                half8_t bh = *(const half8_t*)&Hs[(nt * 16 + c) * 72 + kt * 32 + q * 8];
                acc[0][nt] = __builtin_amdgcn_mfma_f32_16x16x32_f16(a0, bh, acc[0][nt], 0, 0, 0);
                acc[1][nt] = __builtin_amdgcn_mfma_f32_16x16x32_f16(a1, bh, acc[1][nt], 0, 0, 0);
            }
        }
        __syncthreads();
    }

    // D: lane(c,q) reg r -> o = m0 + q*4 + r, r-row = n0 + c
#pragma unroll
    for (int mt = 0; mt < 2; ++mt) {
        const int obase = (w * 2 + mt) * 16 + q * 4;
        float4 bf = *(const float4*)&bfc[obase];
#pragma unroll
        for (int nt = 0; nt < 4; ++nt) {
            float4 v = {fast_tanh(acc[mt][nt].x + bf.x), fast_tanh(acc[mt][nt].y + bf.y),
                        fast_tanh(acc[mt][nt].z + bf.z), fast_tanh(acc[mt][nt].w + bf.w)};
            *(float4*)&y[(size_t)(r0 + nt * 16 + c) * DIN + obase] = v;
        }
    }
}

// ---------------------------------------------------------------- launch
extern "C" void kernel_launch(void* const* d_in, const int* in_sizes, int n_in,
                              void* d_out, int out_size, void* d_ws, size_t ws_size,
                              hipStream_t stream) {
    (void)in_sizes; (void)n_in; (void)out_size; (void)ws_size;
    const float* x   = (const float*)d_in[0];
    const float* Wih = (const float*)d_in[1];
    const float* Whh = (const float*)d_in[2];
    const float* bih = (const float*)d_in[3];
    const float* bhh = (const float*)d_in[4];
    const float* Wfc = (const float*)d_in[5];
    const float* bfc = (const float*)d_in[6];
    float* y = (float*)d_out;

    half_t* pre = (half_t*)d_ws;                                        // pre[b][l][h]: 64 MB
    half_t* hs  = (half_t*)((char*)d_ws + (size_t)B_ * LEN * DS * 2);   // hs[(l*B+b)][s]: 64 MB

    hipFuncSetAttribute((const void*)rnn_recur_kernel,
                        hipFuncAttributeMaxDynamicSharedMemorySize, LDS_BYTES);

    rnn_pre_kernel<<<dim3(LEN / 64, B_, DS / 128), 256, 0, stream>>>(x, Wih, bih, bhh, pre);
    rnn_recur_kernel<<<dim3(B_), 512, LDS_BYTES, stream>>>(Whh, pre, hs);
    rnn_out_kernel<<<dim3(LEN * B_ / 64), 256, 0, stream>>>(hs, Wfc, bfc, y);
}